// Round 2
// baseline (102.280 us; speedup 1.0000x reference)
//
#include <hip/hip_runtime.h>

// ASTDecoder: batched GCN on a fixed banded graph (i<->i+1, i<->i+2), 2048
// graphs x 256 nodes. Key structure: initial node features are uniform per
// graph, the propagation matrix has row-sum 1 for interior nodes, and the
// graph is reflection-symmetric. After L layers only nodes 0..(2L+1) (and the
// mirrored tail) differ from one shared interior row. So per graph we track
// at most 8 boundary rows + 1 interior row of 64 features, run tiny GEMVs,
// and broadcast 9 distinct 128-float output rows into the 256x128 output.
// The kernel is then bound by the 256 MiB output write.

#define NB   2048   // batch (graphs)
#define EMB  256
#define HID  64
#define ODIM 128
#define NN   256    // nodes per graph

typedef float f32x4 __attribute__((ext_vector_type(4)));  // native vec for nontemporal

__device__ __forceinline__ float dinvf(int j) {
  // deg = 3 (node 0), 4 (node 1), 5 (nodes 2..253); only j<=9 ever queried.
  if (j == 0) return 0.57735026918962576f;  // 1/sqrt(3)
  if (j == 1) return 0.5f;                  // 1/sqrt(4)
  return 0.44721359549995794f;              // 1/sqrt(5)
}

__global__ __launch_bounds__(256) void gcn_fused(
    const float* __restrict__ emb,
    const float* __restrict__ W_emb,
    const float* __restrict__ b_emb,
    const float* __restrict__ convW,
    const float* __restrict__ convB,
    const float* __restrict__ Wout,
    const float* __restrict__ bout,
    float* __restrict__ out)
{
  const int b   = blockIdx.x;
  const int tid = threadIdx.x;

  __shared__ __align__(16) float e_s[EMB];
  __shared__ __align__(16) float X[9][HID];   // rows 0..7 = boundary nodes, 8 = interior
  __shared__ __align__(16) float G[9][HID];   // per-layer h = x @ W rows
  __shared__ __align__(16) float O[9][ODIM];  // distinct output rows

  // stage embedding row (coalesced 1 KB)
  e_s[tid] = emb[(size_t)b * EMB + tid];
  __syncthreads();

  // v = emb[b] @ W_emb + b_emb  -> interior row X[8]; nd = 0 distinct boundary rows
  if (tid < HID) {
    float acc = b_emb[tid];
    #pragma unroll 8
    for (int k = 0; k < EMB; ++k)
      acc = fmaf(e_s[k], W_emb[k * HID + tid], acc);  // W column read coalesced over tid
    X[8][tid] = acc;
  }
  __syncthreads();

  int nd = 0;  // number of distinct boundary rows (nodes 0..nd-1)
  #pragma unroll
  for (int l = 0; l < 3; ++l) {
    const float* W  = convW + l * HID * HID;
    const float* bb = convB + l * HID;

    // G[r] = X[r] @ W for r < nd, plus interior G[8] = X[8] @ W
    const int nG = nd + 1;
    {
      const int rloc = tid >> 6, j = tid & 63;
      for (int base = 0; base < nG; base += 4) {
        const int r = base + rloc;
        if (r < nG) {
          const int xr = (r < nd) ? r : 8;
          float acc = 0.f;
          #pragma unroll
          for (int k = 0; k < HID; ++k)
            acc = fmaf(X[xr][k], W[k * HID + j], acc);
          G[xr][j] = acc;
        }
      }
    }
    __syncthreads();

    // new distinct width: P-rows differ for i<=3, input non-uniformity spreads +2
    const int ndn = (nd + 2 < 4) ? 4 : (nd + 2);
    {
      const int iloc = tid >> 6, j = tid & 63;
      for (int base = 0; base < ndn; base += 4) {
        const int i = base + iloc;
        if (i < ndn) {
          const float di = dinvf(i);
          float acc = 0.f;
          const int j0 = (i >= 2) ? (i - 2) : 0;
          for (int jj = j0; jj <= i + 2; ++jj)
            acc = fmaf(di * dinvf(jj), G[(jj < nd) ? jj : 8][j], acc);
          X[i][j] = fmaxf(acc + bb[j], 0.f);
        }
      }
      if (tid < HID)  // interior: row-sum of P is exactly 1
        X[8][tid] = fmaxf(G[8][tid] + bb[tid], 0.f);
    }
    __syncthreads();
    nd = ndn;
  }
  // nd == 8: distinct rows are nodes 0..7 + interior (nodes 8..247); 248..255 mirror 7..0.

  // O[r] = X[r] @ W_out + b_out, 9 rows x 128 cols
  {
    const int rloc = tid >> 7, j = tid & 127;
    for (int base = 0; base < 9; base += 2) {
      const int r = base + rloc;
      if (r < 9) {
        float acc = bout[j];
        #pragma unroll
        for (int k = 0; k < HID; ++k)
          acc = fmaf(X[r][k], Wout[k * ODIM + j], acc);
        O[r][j] = acc;
      }
    }
  }
  __syncthreads();

  // broadcast-write 256x128 f32 (128 KiB) fully coalesced, f32x4 nontemporal
  f32x4* outg = reinterpret_cast<f32x4*>(out + (size_t)b * NN * ODIM);
  const int lane32 = tid & 31;
  const int nsub   = tid >> 5;  // 0..7
  const f32x4 vint = *reinterpret_cast<const f32x4*>(&O[8][lane32 * 4]);
  for (int i0 = 0; i0 < NN; i0 += 8) {
    const int node = i0 + nsub;
    f32x4 v;
    if (node < 8)              v = *reinterpret_cast<const f32x4*>(&O[node][lane32 * 4]);
    else if (node >= NN - 8)   v = *reinterpret_cast<const f32x4*>(&O[NN - 1 - node][lane32 * 4]);
    else                       v = vint;
    __builtin_nontemporal_store(v, &outg[node * 32 + lane32]);
  }
}

extern "C" void kernel_launch(void* const* d_in, const int* in_sizes, int n_in,
                              void* d_out, int out_size, void* d_ws, size_t ws_size,
                              hipStream_t stream) {
  const float* emb   = (const float*)d_in[0];
  const float* W_emb = (const float*)d_in[1];
  const float* b_emb = (const float*)d_in[2];
  const float* convW = (const float*)d_in[3];
  const float* convB = (const float*)d_in[4];
  const float* Wout  = (const float*)d_in[5];
  const float* bout  = (const float*)d_in[6];
  // d_in[7] = target_num_nodes (256) — structure hardcoded to match reference.
  float* out = (float*)d_out;

  hipLaunchKernelGGL(gcn_fused, dim3(NB), dim3(256), 0, stream,
                     emb, W_emb, b_emb, convW, convB, Wout, bout, out);
}

// Round 3
// 91.803 us; speedup vs baseline: 1.1141x; 1.1141x over previous
//
#include <hip/hip_runtime.h>

// ASTDecoder: batched GCN on a fixed banded graph (i<->i+1, i<->i+2), 2048
// graphs x 256 nodes. Only 9 distinct feature rows per graph survive 3 GCN
// layers (8 boundary rows + 1 interior; tail mirrors head). Round 2 fused
// kernel hit 102us vs a ~39us write roofline (fill kernel proves 6.9 TB/s):
// the VGPR-heavy compute prologue capped occupancy and serialized against
// the write burst. This round splits:
//   A) compute_O: per-graph 9x128 output-row table -> d_ws (9.4 MB)
//   B) bcast_write: occupancy-friendly pure broadcast write of 268 MB.

#define NB   2048   // batch (graphs)
#define EMB  256
#define HID  64
#define ODIM 128
#define NN   256    // nodes per graph
#define NROW 9      // distinct rows per graph (0..7 boundary, 8 interior)

typedef float f32x4 __attribute__((ext_vector_type(4)));

__device__ __forceinline__ float dinvf(int j) {
  // deg = 3 (node 0), 4 (node 1), 5 (nodes 2..253); only j<=9 ever queried.
  if (j == 0) return 0.57735026918962576f;  // 1/sqrt(3)
  if (j == 1) return 0.5f;                  // 1/sqrt(4)
  return 0.44721359549995794f;              // 1/sqrt(5)
}

// ---------------- Kernel A: per-graph distinct-row table ----------------
__global__ __launch_bounds__(256) void compute_O(
    const float* __restrict__ emb,
    const float* __restrict__ W_emb,
    const float* __restrict__ b_emb,
    const float* __restrict__ convW,
    const float* __restrict__ convB,
    const float* __restrict__ Wout,
    const float* __restrict__ bout,
    float* __restrict__ Ot)   // [NB][NROW][ODIM]
{
  const int b   = blockIdx.x;
  const int tid = threadIdx.x;

  __shared__ __align__(16) float e_s[EMB];
  __shared__ __align__(16) float X[9][HID];   // rows 0..7 boundary, 8 interior
  __shared__ __align__(16) float G[9][HID];
  __shared__ __align__(16) float O[NROW][ODIM];

  e_s[tid] = emb[(size_t)b * EMB + tid];
  __syncthreads();

  // interior init row: v = emb[b] @ W_emb + b_emb
  if (tid < HID) {
    float acc = b_emb[tid];
    #pragma unroll 8
    for (int k = 0; k < EMB; ++k)
      acc = fmaf(e_s[k], W_emb[k * HID + tid], acc);
    X[8][tid] = acc;
  }
  __syncthreads();

  int nd = 0;  // distinct boundary rows
  #pragma unroll
  for (int l = 0; l < 3; ++l) {
    const float* W  = convW + l * HID * HID;
    const float* bb = convB + l * HID;

    const int nG = nd + 1;
    {
      const int rloc = tid >> 6, j = tid & 63;
      for (int base = 0; base < nG; base += 4) {
        const int r = base + rloc;
        if (r < nG) {
          const int xr = (r < nd) ? r : 8;
          float acc = 0.f;
          #pragma unroll 16
          for (int k = 0; k < HID; ++k)
            acc = fmaf(X[xr][k], W[k * HID + j], acc);
          G[xr][j] = acc;
        }
      }
    }
    __syncthreads();

    const int ndn = (nd + 2 < 4) ? 4 : (nd + 2);
    {
      const int iloc = tid >> 6, j = tid & 63;
      for (int base = 0; base < ndn; base += 4) {
        const int i = base + iloc;
        if (i < ndn) {
          const float di = dinvf(i);
          float acc = 0.f;
          const int j0 = (i >= 2) ? (i - 2) : 0;
          for (int jj = j0; jj <= i + 2; ++jj)
            acc = fmaf(di * dinvf(jj), G[(jj < nd) ? jj : 8][j], acc);
          X[i][j] = fmaxf(acc + bb[j], 0.f);
        }
      }
      if (tid < HID)  // interior: P row-sum is exactly 1
        X[8][tid] = fmaxf(G[8][tid] + bb[tid], 0.f);
    }
    __syncthreads();
    nd = ndn;
  }

  // O[r] = X[r] @ W_out + b_out
  {
    const int rloc = tid >> 7, j = tid & 127;
    for (int base = 0; base < NROW; base += 2) {
      const int r = base + rloc;
      if (r < NROW) {
        float acc = bout[j];
        #pragma unroll 16
        for (int k = 0; k < HID; ++k)
          acc = fmaf(X[r][k], Wout[k * ODIM + j], acc);
        O[r][j] = acc;
      }
    }
  }
  __syncthreads();

  // dump table (coalesced)
  float* dstp = Ot + (size_t)b * (NROW * ODIM);
  const float* srcp = &O[0][0];
  for (int idx = tid; idx < NROW * ODIM; idx += 256)
    dstp[idx] = srcp[idx];
}

// ---------------- Kernel B: pure broadcast write ----------------
// One block per half-graph (128 nodes = 64 KB). Low VGPR, 4.5 KB LDS ->
// full occupancy; plain cached f32x4 stores (same path as the 6.9 TB/s fill).
__global__ __launch_bounds__(256) void bcast_write(
    const float* __restrict__ Ot,
    float* __restrict__ out)
{
  const int g   = blockIdx.x >> 1;
  const int h   = blockIdx.x & 1;      // half: nodes [h*128, h*128+128)
  const int tid = threadIdx.x;

  __shared__ __align__(16) float O[NROW][ODIM];
  const float* src = Ot + (size_t)g * (NROW * ODIM);
  for (int idx = tid; idx < NROW * ODIM; idx += 256)
    (&O[0][0])[idx] = src[idx];
  __syncthreads();

  f32x4* outg = reinterpret_cast<f32x4*>(out + (size_t)g * NN * ODIM);
  const int lane32 = tid & 31;
  const int nsub   = tid >> 5;  // 0..7
  const f32x4 vint = *reinterpret_cast<const f32x4*>(&O[8][lane32 * 4]);
  const int nbase  = h * 128;

  for (int i0 = 0; i0 < 128; i0 += 8) {
    const int node = nbase + i0 + nsub;
    f32x4 v;
    if (node < 8)            v = *reinterpret_cast<const f32x4*>(&O[node][lane32 * 4]);
    else if (node >= NN - 8) v = *reinterpret_cast<const f32x4*>(&O[NN - 1 - node][lane32 * 4]);
    else                     v = vint;
    outg[node * 32 + lane32] = v;
  }
}

extern "C" void kernel_launch(void* const* d_in, const int* in_sizes, int n_in,
                              void* d_out, int out_size, void* d_ws, size_t ws_size,
                              hipStream_t stream) {
  const float* emb   = (const float*)d_in[0];
  const float* W_emb = (const float*)d_in[1];
  const float* b_emb = (const float*)d_in[2];
  const float* convW = (const float*)d_in[3];
  const float* convB = (const float*)d_in[4];
  const float* Wout  = (const float*)d_in[5];
  const float* bout  = (const float*)d_in[6];
  float* out = (float*)d_out;
  float* Ot  = (float*)d_ws;   // NB*NROW*ODIM floats = 9.4 MB

  hipLaunchKernelGGL(compute_O, dim3(NB), dim3(256), 0, stream,
                     emb, W_emb, b_emb, convW, convB, Wout, bout, Ot);
  hipLaunchKernelGGL(bcast_write, dim3(NB * 2), dim3(256), 0, stream,
                     Ot, out);
}

// Round 4
// 78.339 us; speedup vs baseline: 1.3056x; 1.1719x over previous
//
#include <hip/hip_runtime.h>

// ASTDecoder: batched GCN on a fixed banded graph (i<->i+1, i<->i+2), 2048
// graphs x 256 nodes. Only 9 distinct feature rows per graph survive 3 GCN
// layers (8 boundary + 1 interior; tail mirrors head).
// R2 fused: 102us. R3 split: 92us -> proves compute (~50us) dominates, write
// is near its ~40us floor (fill kernel: 6.9 TB/s). R4: re-fused, compute
// phase rebuilt for full lane utilization + 2 graphs/block to amortize
// weight reads; all 1024 blocks co-resident so compute (~5us) then a
// fill-like 268 MB write drain.

#define NB   2048   // batch (graphs)
#define EMB  256
#define HID  64
#define ODIM 128
#define NN   256    // nodes per graph
#define NROW 9      // distinct rows per graph (0..7 boundary, 8 interior)
#define MG   2      // graphs per block

typedef float f32x4 __attribute__((ext_vector_type(4)));

__device__ __forceinline__ float dinvf(int j) {
  // deg = 3 (node 0), 4 (node 1), 5 (nodes 2..253); only j<=9 ever queried.
  if (j == 0) return 0.57735026918962576f;  // 1/sqrt(3)
  if (j == 1) return 0.5f;                  // 1/sqrt(4)
  return 0.44721359549995794f;              // 1/sqrt(5)
}

__global__ __launch_bounds__(256) void gcn_fused(
    const float* __restrict__ emb,
    const float* __restrict__ W_emb,
    const float* __restrict__ b_emb,
    const float* __restrict__ convW,
    const float* __restrict__ convB,
    const float* __restrict__ Wout,
    const float* __restrict__ bout,
    float* __restrict__ out)
{
  const int tid   = threadIdx.x;
  const int gbase = blockIdx.x * MG;

  __shared__ __align__(16) float e_s[MG][EMB];
  __shared__ __align__(16) float X[MG][9][HID];
  __shared__ __align__(16) float G[MG][9][HID];
  __shared__ __align__(16) float O[MG][NROW][ODIM];
  __shared__ __align__(16) float red[MG][HID];

  // stage embeddings (MG x 1 KB, coalesced)
  for (int idx = tid; idx < MG * EMB; idx += 256) {
    const int g = idx >> 8, k = idx & 255;
    e_s[g][k] = emb[(size_t)(gbase + g) * EMB + k];
  }
  __syncthreads();

  // init interior row: v = emb @ W_emb + b_emb.
  // split-K: 256 threads = 2 k-halves x MG graphs x 64 outputs.
  {
    const int j = tid & 63, g = (tid >> 6) & 1, half = tid >> 7;
    const int k0 = half * 128;
    float acc = 0.f;
    #pragma unroll 8
    for (int k = 0; k < 128; ++k)
      acc = fmaf(e_s[g][k0 + k], W_emb[(k0 + k) * HID + j], acc);
    if (half) red[g][j] = acc;
    __syncthreads();
    if (!half) X[g][8][j] = acc + red[g][j] + b_emb[j];
  }
  __syncthreads();

  int nd = 0;  // distinct boundary rows
  #pragma unroll
  for (int l = 0; l < 3; ++l) {
    const float* W  = convW + l * HID * HID;
    const float* bb = convB + l * HID;

    // G[g][xr] = X[g][xr] @ W for xr in {0..nd-1, 8}
    const int nG = nd + 1;
    for (int idx = tid; idx < MG * nG * HID; idx += 256) {
      const int j = idx & 63;
      const int t = idx >> 6;               // 0 .. MG*nG-1
      const int g = (t >= nG) ? 1 : 0;
      const int r = t - g * nG;
      const int xr = (r < nd) ? r : 8;
      float acc = 0.f;
      #pragma unroll 8
      for (int k = 0; k < HID; ++k)
        acc = fmaf(X[g][xr][k], W[k * HID + j], acc);
      G[g][xr][j] = acc;
    }
    __syncthreads();

    // mix boundary rows: X[i] = relu(sum_jj P[i][jj] G[jj] + b), i < ndn
    const int ndn = (nd + 2 < 4) ? 4 : (nd + 2);
    for (int idx = tid; idx < MG * ndn * HID; idx += 256) {
      const int j = idx & 63;
      const int t = idx >> 6;
      const int g = (t >= ndn) ? 1 : 0;
      const int i = t - g * ndn;
      const float di = dinvf(i);
      float acc = 0.f;
      const int j0 = (i >= 2) ? (i - 2) : 0;
      for (int jj = j0; jj <= i + 2; ++jj)
        acc = fmaf(di * dinvf(jj), G[g][(jj < nd) ? jj : 8][j], acc);
      X[g][i][j] = fmaxf(acc + bb[j], 0.f);
    }
    // interior: P row-sum is exactly 1
    for (int idx = tid; idx < MG * HID; idx += 256) {
      const int j = idx & 63, g = idx >> 6;
      X[g][8][j] = fmaxf(G[g][8][j] + bb[j], 0.f);
    }
    __syncthreads();
    nd = ndn;
  }

  // O[g][r] = X[g][r] @ W_out + b_out  (MG*9*128 = 2304 outputs)
  for (int idx = tid; idx < MG * NROW * ODIM; idx += 256) {
    const int j = idx & 127;
    const int t = idx >> 7;                 // 0..17
    const int g = (t >= NROW) ? 1 : 0;
    const int r = t - g * NROW;
    float acc = bout[j];
    #pragma unroll 8
    for (int k = 0; k < HID; ++k)
      acc = fmaf(X[g][r][k], Wout[k * ODIM + j], acc);
    O[g][r][j] = acc;
  }
  __syncthreads();

  // broadcast-write MG x 256x128 f32, fully coalesced (1 KB/wave-instr),
  // nontemporal: out (268 MB) exceeds L3, never re-read.
  const int lane32 = tid & 31;
  const int nsub   = tid >> 5;  // 0..7
  #pragma unroll
  for (int g = 0; g < MG; ++g) {
    f32x4* outg = reinterpret_cast<f32x4*>(out + (size_t)(gbase + g) * NN * ODIM);
    const f32x4 vint = *reinterpret_cast<const f32x4*>(&O[g][8][lane32 * 4]);
    for (int i0 = 0; i0 < NN; i0 += 8) {
      const int node = i0 + nsub;
      f32x4 v;
      if (node < 8)            v = *reinterpret_cast<const f32x4*>(&O[g][node][lane32 * 4]);
      else if (node >= NN - 8) v = *reinterpret_cast<const f32x4*>(&O[g][NN - 1 - node][lane32 * 4]);
      else                     v = vint;
      __builtin_nontemporal_store(v, &outg[node * 32 + lane32]);
    }
  }
}

extern "C" void kernel_launch(void* const* d_in, const int* in_sizes, int n_in,
                              void* d_out, int out_size, void* d_ws, size_t ws_size,
                              hipStream_t stream) {
  const float* emb   = (const float*)d_in[0];
  const float* W_emb = (const float*)d_in[1];
  const float* b_emb = (const float*)d_in[2];
  const float* convW = (const float*)d_in[3];
  const float* convB = (const float*)d_in[4];
  const float* Wout  = (const float*)d_in[5];
  const float* bout  = (const float*)d_in[6];
  float* out = (float*)d_out;

  hipLaunchKernelGGL(gcn_fused, dim3(NB / MG), dim3(256), 0, stream,
                     emb, W_emb, b_emb, convW, convB, Wout, bout, out);
}

// Round 5
// 73.197 us; speedup vs baseline: 1.3973x; 1.0702x over previous
//
#include <hip/hip_runtime.h>

// ASTDecoder: batched GCN on a fixed banded graph (i<->i+1, i<->i+2), 2048
// graphs x 256 nodes. Only 9 distinct feature rows per graph survive 3 GCN
// layers (8 boundary + 1 interior; tail mirrors head).
// R2 fused 102us -> R3 split 92us -> R4 fused+parallel 78us. Write floor is
// ~40us (fill: 6.9 TB/s). Remaining gap was weight traffic: per-(row,col)
// GEMV items each re-read whole weight columns (~1.1 GB L2 aggregate).
// R5: column-per-thread GEMVs — load W[k][j] once, apply to all rows and all
// MG=4 graphs in registers. Weight traffic per block ~= one pass over W.

#define NB   2048
#define EMB  256
#define HID  64
#define ODIM 128
#define NN   256
#define NROW 9
#define MG   4      // graphs per block
#define NBLK (NB / MG)

typedef float f32x4 __attribute__((ext_vector_type(4)));

__device__ __forceinline__ float dinvf(int j) {
  // deg = 3 (node 0), 4 (node 1), 5 (nodes 2..253); only j<=9 ever queried.
  if (j == 0) return 0.57735026918962576f;
  if (j == 1) return 0.5f;
  return 0.44721359549995794f;
}

struct Smem {
  float e_s[MG][EMB];        // 4 KB
  float X[MG][NROW][HID];    // 9 KB
  float G[MG][NROW][HID];    // 9 KB
  float O[MG][NROW][ODIM];   // 18 KB
  float red[4][MG][HID];     // 4 KB  (init split-K partials)
};

// One GCN layer with nd distinct boundary rows on entry (compile-time).
template <int ND>
__device__ __forceinline__ void layer_step(Smem& s, const float* __restrict__ W,
                                           const float* __restrict__ bb, int tid) {
  constexpr int NG  = ND + 1;                      // rows to transform (incl. interior)
  constexpr int NDN = (ND + 2 < 4) ? 4 : (ND + 2); // distinct rows on exit

  // G[g][row] = X[g][row] @ W — thread = (graph g, output col j).
  {
    const int g = tid >> 6, j = tid & 63;
    float acc[NG];
    #pragma unroll
    for (int r = 0; r < NG; ++r) acc[r] = 0.f;
    for (int k0 = 0; k0 < HID; k0 += 4) {
      const float w0 = W[(k0 + 0) * HID + j];
      const float w1 = W[(k0 + 1) * HID + j];
      const float w2 = W[(k0 + 2) * HID + j];
      const float w3 = W[(k0 + 3) * HID + j];
      #pragma unroll
      for (int r = 0; r < NG; ++r) {
        const int xr = (r < ND) ? r : 8;
        const f32x4 x = *reinterpret_cast<const f32x4*>(&s.X[g][xr][k0]);
        acc[r] = fmaf(x[0], w0, acc[r]);
        acc[r] = fmaf(x[1], w1, acc[r]);
        acc[r] = fmaf(x[2], w2, acc[r]);
        acc[r] = fmaf(x[3], w3, acc[r]);
      }
    }
    #pragma unroll
    for (int r = 0; r < NG; ++r)
      s.G[g][(r < ND) ? r : 8][j] = acc[r];
  }
  __syncthreads();

  // Boundary mix: X[i] = relu(sum_jj P[i][jj] G[jj] + b), i < NDN.
  for (int idx = tid; idx < MG * NDN * HID; idx += 256) {
    const int j = idx & 63;
    const int t = idx >> 6;
    const int g = t / NDN;         // NDN is constexpr -> folds
    const int i = t - g * NDN;
    const float di = dinvf(i);
    float acc = 0.f;
    const int j0 = (i >= 2) ? (i - 2) : 0;
    for (int jj = j0; jj <= i + 2; ++jj)
      acc = fmaf(di * dinvf(jj), s.G[g][(jj < ND) ? jj : 8][j], acc);
    s.X[g][i][j] = fmaxf(acc + bb[j], 0.f);
  }
  // Interior: P row-sum is exactly 1.
  {
    const int g = tid >> 6, j = tid & 63;
    s.X[g][8][j] = fmaxf(s.G[g][8][j] + bb[j], 0.f);
  }
  __syncthreads();
}

__global__ __launch_bounds__(256) void gcn_fused(
    const float* __restrict__ emb,
    const float* __restrict__ W_emb,
    const float* __restrict__ b_emb,
    const float* __restrict__ convW,
    const float* __restrict__ convB,
    const float* __restrict__ Wout,
    const float* __restrict__ bout,
    float* __restrict__ out)
{
  const int tid   = threadIdx.x;
  const int gbase = blockIdx.x * MG;

  __shared__ __align__(16) Smem s;

  // stage embeddings (4 KB, coalesced)
  for (int idx = tid; idx < MG * EMB; idx += 256) {
    const int g = idx >> 8, k = idx & 255;
    s.e_s[g][k] = emb[(size_t)(gbase + g) * EMB + k];
  }
  __syncthreads();

  // init interior: v = emb @ W_emb + b_emb. split-K 4-way; each thread reads
  // its W element once and applies to all MG graphs.
  {
    const int q = tid >> 6, j = tid & 63;  // k-quarter, output col
    float a0 = 0.f, a1 = 0.f, a2 = 0.f, a3 = 0.f;
    const int k0 = q * 64;
    #pragma unroll 8
    for (int k = 0; k < 64; ++k) {
      const float w = W_emb[(k0 + k) * HID + j];
      a0 = fmaf(s.e_s[0][k0 + k], w, a0);
      a1 = fmaf(s.e_s[1][k0 + k], w, a1);
      a2 = fmaf(s.e_s[2][k0 + k], w, a2);
      a3 = fmaf(s.e_s[3][k0 + k], w, a3);
    }
    s.red[q][0][j] = a0; s.red[q][1][j] = a1;
    s.red[q][2][j] = a2; s.red[q][3][j] = a3;
  }
  __syncthreads();
  {
    const int g = tid >> 6, j = tid & 63;
    s.X[g][8][j] = s.red[0][g][j] + s.red[1][g][j] + s.red[2][g][j]
                 + s.red[3][g][j] + b_emb[j];
  }
  __syncthreads();

  // 3 GCN layers; nd = 0 -> 4 -> 6 -> 8 distinct boundary rows.
  layer_step<0>(s, convW + 0 * HID * HID, convB + 0 * HID, tid);
  layer_step<4>(s, convW + 1 * HID * HID, convB + 1 * HID, tid);
  layer_step<6>(s, convW + 2 * HID * HID, convB + 2 * HID, tid);

  // Final: O[g][r] = X[g][r] @ W_out + b_out. Thread = (pair p, col j);
  // handles graphs {p, p+2}, all 9 rows, reading each Wout element once.
  {
    const int p = tid >> 7, j = tid & 127;
    const int gA = p, gB = p + 2;
    float accA[NROW], accB[NROW];
    #pragma unroll
    for (int r = 0; r < NROW; ++r) { accA[r] = 0.f; accB[r] = 0.f; }
    for (int k0 = 0; k0 < HID; k0 += 4) {
      const float w0 = Wout[(k0 + 0) * ODIM + j];
      const float w1 = Wout[(k0 + 1) * ODIM + j];
      const float w2 = Wout[(k0 + 2) * ODIM + j];
      const float w3 = Wout[(k0 + 3) * ODIM + j];
      #pragma unroll
      for (int r = 0; r < NROW; ++r) {
        const f32x4 xa = *reinterpret_cast<const f32x4*>(&s.X[gA][r][k0]);
        const f32x4 xb = *reinterpret_cast<const f32x4*>(&s.X[gB][r][k0]);
        accA[r] = fmaf(xa[0], w0, accA[r]); accA[r] = fmaf(xa[1], w1, accA[r]);
        accA[r] = fmaf(xa[2], w2, accA[r]); accA[r] = fmaf(xa[3], w3, accA[r]);
        accB[r] = fmaf(xb[0], w0, accB[r]); accB[r] = fmaf(xb[1], w1, accB[r]);
        accB[r] = fmaf(xb[2], w2, accB[r]); accB[r] = fmaf(xb[3], w3, accB[r]);
      }
    }
    const float bj = bout[j];
    #pragma unroll
    for (int r = 0; r < NROW; ++r) {
      s.O[gA][r][j] = accA[r] + bj;
      s.O[gB][r][j] = accB[r] + bj;
    }
  }
  __syncthreads();

  // broadcast-write MG x 256x128 f32, fully coalesced, nontemporal (268 MB
  // total, > L3, never re-read).
  const int lane32 = tid & 31;
  const int nsub   = tid >> 5;  // 0..7
  #pragma unroll
  for (int g = 0; g < MG; ++g) {
    f32x4* outg = reinterpret_cast<f32x4*>(out + (size_t)(gbase + g) * NN * ODIM);
    const f32x4 vint = *reinterpret_cast<const f32x4*>(&s.O[g][8][lane32 * 4]);
    for (int i0 = 0; i0 < NN; i0 += 8) {
      const int node = i0 + nsub;
      f32x4 v;
      if (node < 8)            v = *reinterpret_cast<const f32x4*>(&s.O[g][node][lane32 * 4]);
      else if (node >= NN - 8) v = *reinterpret_cast<const f32x4*>(&s.O[g][NN - 1 - node][lane32 * 4]);
      else                     v = vint;
      __builtin_nontemporal_store(v, &outg[node * 32 + lane32]);
    }
  }
}

extern "C" void kernel_launch(void* const* d_in, const int* in_sizes, int n_in,
                              void* d_out, int out_size, void* d_ws, size_t ws_size,
                              hipStream_t stream) {
  const float* emb   = (const float*)d_in[0];
  const float* W_emb = (const float*)d_in[1];
  const float* b_emb = (const float*)d_in[2];
  const float* convW = (const float*)d_in[3];
  const float* convB = (const float*)d_in[4];
  const float* Wout  = (const float*)d_in[5];
  const float* bout  = (const float*)d_in[6];
  float* out = (float*)d_out;

  hipLaunchKernelGGL(gcn_fused, dim3(NBLK), dim3(256), 0, stream,
                     emb, W_emb, b_emb, convW, convB, Wout, bout, out);
}

// Round 6
// 65.629 us; speedup vs baseline: 1.5585x; 1.1153x over previous
//
#include <hip/hip_runtime.h>

// ASTDecoder: batched GCN on a fixed banded graph (i<->i+1, i<->i+2), 2048
// graphs x 256 nodes. Only 9 distinct rows/graph survive 3 layers (8 boundary
// + 1 interior; tail mirrors head). History: R2 102us -> R3 92 -> R4 78 ->
// R5 73. Write floor ~39us (fill: 6.9 TB/s). R5's remaining ~33us was a
// serial compute head (LDS-instruction-issue bound) with HBM idle.
// R6: wave specialization. 512-thread blocks, wave g (0..3) = graph g's
// INTERIOR path: init + 1-row chain + O8, then immediately streams the 240
// interior nodes (94% of bytes). Waves 4..7 = BOUNDARY path for graph g-4
// (private chain copy + 8 boundary rows in registers/LDS + final), running
// concurrently under the interior store drain; writes 16 boundary nodes at
// the end. All post-init handoffs are intra-wave (lockstep) -> only 2
// __syncthreads, both before any store.

#define NB   2048
#define EMB  256
#define HID  64
#define ODIM 128
#define NN   256
#define MG   4            // graphs per block
#define NBLK (NB / MG)    // 512 blocks x 512 threads = 2 blocks/CU

typedef float f32x4 __attribute__((ext_vector_type(4)));

__device__ __forceinline__ float dinvf(int j) {
  // deg: node0=3, node1=4, nodes 2..253=5 (mirror symmetric); only j<=9 used.
  if (j == 0) return 0.57735026918962576f;  // 1/sqrt(3)
  if (j == 1) return 0.5f;                  // 1/sqrt(4)
  return 0.44721359549995794f;              // 1/sqrt(5)
}

struct Smem {
  float e[MG][EMB];        // 4 KB   staged embeddings
  float red[8][MG][HID];   // 8 KB   init split-K partials
  float X8s[MG][4][HID];   // 4 KB   interior chain levels 0..3 (interior waves)
  float X8b[MG][4][HID];   // 4 KB   boundary waves' private chain copy
  float Xb[MG][8][HID];    // 8 KB   boundary rows
  float O8[MG][ODIM];      // 2 KB   interior output row
  float Ob[MG][8][ODIM];   // 16 KB  boundary output rows
};                         // 46 KB -> 2 blocks/CU

// One boundary-path GCN layer. Chain step (g8) + ND_IN boundary-row GEMVs
// (accumulators in registers, X broadcast-read from LDS) + banded mix.
// All LDS deps are same-wave (lockstep).
template <int L, int ND_IN>
__device__ __forceinline__ void boundary_layer(Smem& s, int g, int j,
                                               const float* __restrict__ convW,
                                               const float* __restrict__ convB) {
  const float* W  = convW + L * HID * HID;
  const float* bb = convB + L * HID;

  // interior-row chain step: g8 = X8^L @ W (col j), pre-bias/pre-relu
  float g8 = 0.f;
  #pragma unroll
  for (int k0 = 0; k0 < HID; k0 += 4) {
    const f32x4 xv = *reinterpret_cast<const f32x4*>(&s.X8b[g][L][k0]);
    g8 = fmaf(xv[0], W[(k0 + 0) * HID + j], g8);
    g8 = fmaf(xv[1], W[(k0 + 1) * HID + j], g8);
    g8 = fmaf(xv[2], W[(k0 + 2) * HID + j], g8);
    g8 = fmaf(xv[3], W[(k0 + 3) * HID + j], g8);
  }
  s.X8b[g][L + 1][j] = fmaxf(g8 + bb[j], 0.f);

  // boundary G rows (registers, compile-time indexed)
  float accR[ND_IN > 0 ? ND_IN : 1];
  #pragma unroll
  for (int r = 0; r < (ND_IN > 0 ? ND_IN : 1); ++r) accR[r] = 0.f;
  if constexpr (ND_IN > 0) {
    #pragma unroll
    for (int k0 = 0; k0 < HID; k0 += 4) {
      float w[4];
      #pragma unroll
      for (int c = 0; c < 4; ++c) w[c] = W[(k0 + c) * HID + j];
      #pragma unroll
      for (int r = 0; r < ND_IN; ++r) {
        const f32x4 xv = *reinterpret_cast<const f32x4*>(&s.Xb[g][r][k0]);
        accR[r] = fmaf(xv[0], w[0], accR[r]);
        accR[r] = fmaf(xv[1], w[1], accR[r]);
        accR[r] = fmaf(xv[2], w[2], accR[r]);
        accR[r] = fmaf(xv[3], w[3], accR[r]);
      }
    }
  }

  // banded mix: X'[i] = relu(sum_jj P[i][jj] * Gval(jj) + b), i < NDN
  constexpr int NDN = (ND_IN + 2 < 4) ? 4 : (ND_IN + 2);
  float xnew[NDN];
  #pragma unroll
  for (int i = 0; i < NDN; ++i) {
    const float di = dinvf(i);
    float acc = 0.f;
    #pragma unroll
    for (int jj = (i >= 2 ? i - 2 : 0); jj <= i + 2; ++jj) {
      const float v = (jj < ND_IN) ? accR[jj] : g8;
      acc = fmaf(di * dinvf(jj), v, acc);
    }
    xnew[i] = fmaxf(acc + bb[j], 0.f);
  }
  #pragma unroll
  for (int i = 0; i < NDN; ++i) s.Xb[g][i][j] = xnew[i];
}

__global__ __launch_bounds__(512) void gcn_fused(
    const float* __restrict__ emb,
    const float* __restrict__ W_emb,
    const float* __restrict__ b_emb,
    const float* __restrict__ convW,
    const float* __restrict__ convB,
    const float* __restrict__ Wout,
    const float* __restrict__ bout,
    float* __restrict__ out)
{
  const int tid   = threadIdx.x;
  const int lane  = tid & 63;
  const int wid   = tid >> 6;          // 0..7
  const int gbase = blockIdx.x * MG;

  __shared__ __align__(16) Smem s;

  // stage embeddings: 256 f32x4 (1 KB/wave-instr, coalesced)
  if (tid < MG * EMB / 4) {
    const int g = tid >> 6, q = tid & 63;
    *reinterpret_cast<f32x4*>(&s.e[g][q * 4]) =
        *reinterpret_cast<const f32x4*>(&emb[(size_t)(gbase + g) * EMB + q * 4]);
  }
  __syncthreads();

  // init split-K: wid = k-eighth (32 k's), lane = output col j, all MG graphs
  {
    const int k0 = wid * 32, j = lane;
    float a[MG] = {0.f, 0.f, 0.f, 0.f};
    #pragma unroll
    for (int kk = 0; kk < 32; kk += 4) {
      float w[4];
      #pragma unroll
      for (int c = 0; c < 4; ++c) w[c] = W_emb[(k0 + kk + c) * HID + j];
      #pragma unroll
      for (int g = 0; g < MG; ++g) {
        const f32x4 ev = *reinterpret_cast<const f32x4*>(&s.e[g][k0 + kk]);
        a[g] = fmaf(ev[0], w[0], a[g]);
        a[g] = fmaf(ev[1], w[1], a[g]);
        a[g] = fmaf(ev[2], w[2], a[g]);
        a[g] = fmaf(ev[3], w[3], a[g]);
      }
    }
    #pragma unroll
    for (int g = 0; g < MG; ++g) s.red[wid][g][lane] = a[g];
  }
  __syncthreads();   // last barrier — everything after is intra-wave

  const int g = wid & 3, j = lane;

  // reduce init partials (both wave groups, each into its own chain base)
  {
    float v = b_emb[j];
    #pragma unroll
    for (int kq = 0; kq < 8; ++kq) v += s.red[kq][g][j];
    if (wid < 4) s.X8s[g][0][j] = v;
    else         s.X8b[g][0][j] = v;
  }

  if (wid < 4) {
    // ================= interior path (wave g) =================
    #pragma unroll
    for (int l = 0; l < 3; ++l) {
      const float* W = convW + l * HID * HID;
      float acc = 0.f;
      #pragma unroll
      for (int k0 = 0; k0 < HID; k0 += 4) {
        const f32x4 xv = *reinterpret_cast<const f32x4*>(&s.X8s[g][l][k0]);
        acc = fmaf(xv[0], W[(k0 + 0) * HID + j], acc);
        acc = fmaf(xv[1], W[(k0 + 1) * HID + j], acc);
        acc = fmaf(xv[2], W[(k0 + 2) * HID + j], acc);
        acc = fmaf(xv[3], W[(k0 + 3) * HID + j], acc);
      }
      s.X8s[g][l + 1][j] = fmaxf(acc + convB[l * HID + j], 0.f);
    }
    // interior output row: O8 = X8^3 @ Wout + bout (cols j, j+64)
    float a0 = bout[j], a1 = bout[j + 64];
    #pragma unroll
    for (int k0 = 0; k0 < HID; k0 += 4) {
      const f32x4 xv = *reinterpret_cast<const f32x4*>(&s.X8s[g][3][k0]);
      #pragma unroll
      for (int c = 0; c < 4; ++c) {
        a0 = fmaf(xv[c], Wout[(k0 + c) * ODIM + j], a0);
        a1 = fmaf(xv[c], Wout[(k0 + c) * ODIM + j + 64], a1);
      }
    }
    s.O8[g][j] = a0;
    s.O8[g][j + 64] = a1;

    // stream interior nodes 8..247 (240 x 512 B), contiguous 1 KB/wave-instr
    f32x4* outg = reinterpret_cast<f32x4*>(out + (size_t)(gbase + g) * NN * ODIM);
    const int q = lane & 31, half = lane >> 5;
    const f32x4 vint = *reinterpret_cast<const f32x4*>(&s.O8[g][q * 4]);
    #pragma unroll 8
    for (int it = 0; it < 120; ++it) {
      const int node = 8 + it * 2 + half;
      __builtin_nontemporal_store(vint, &outg[node * 32 + q]);
    }
  } else {
    // ================= boundary path (wave g+4) =================
    boundary_layer<0, 0>(s, g, j, convW, convB);
    boundary_layer<1, 4>(s, g, j, convW, convB);
    boundary_layer<2, 6>(s, g, j, convW, convB);

    // boundary final: rows 0..7, cols {j, j+64}
    float aa[8], ab[8];
    #pragma unroll
    for (int r = 0; r < 8; ++r) { aa[r] = bout[j]; ab[r] = bout[j + 64]; }
    #pragma unroll
    for (int k0 = 0; k0 < HID; k0 += 4) {
      float w0[4], w1[4];
      #pragma unroll
      for (int c = 0; c < 4; ++c) {
        w0[c] = Wout[(k0 + c) * ODIM + j];
        w1[c] = Wout[(k0 + c) * ODIM + j + 64];
      }
      #pragma unroll
      for (int r = 0; r < 8; ++r) {
        const f32x4 xv = *reinterpret_cast<const f32x4*>(&s.Xb[g][r][k0]);
        #pragma unroll
        for (int c = 0; c < 4; ++c) {
          aa[r] = fmaf(xv[c], w0[c], aa[r]);
          ab[r] = fmaf(xv[c], w1[c], ab[r]);
        }
      }
    }
    #pragma unroll
    for (int r = 0; r < 8; ++r) {
      s.Ob[g][r][j] = aa[r];
      s.Ob[g][r][j + 64] = ab[r];
    }

    // write 16 boundary nodes: 0..7 and mirrored 248..255
    f32x4* outg = reinterpret_cast<f32x4*>(out + (size_t)(gbase + g) * NN * ODIM);
    const int q = lane & 31, half = lane >> 5;
    #pragma unroll
    for (int it = 0; it < 8; ++it) {
      const int n    = it * 2 + half;            // 0..15
      const int node = (n < 8) ? n : 240 + n;    // 0..7, 248..255
      const int row  = (n < 8) ? n : 15 - n;     // mirror
      const f32x4 v = *reinterpret_cast<const f32x4*>(&s.Ob[g][row][q * 4]);
      __builtin_nontemporal_store(v, &outg[node * 32 + q]);
    }
  }
}

extern "C" void kernel_launch(void* const* d_in, const int* in_sizes, int n_in,
                              void* d_out, int out_size, void* d_ws, size_t ws_size,
                              hipStream_t stream) {
  const float* emb   = (const float*)d_in[0];
  const float* W_emb = (const float*)d_in[1];
  const float* b_emb = (const float*)d_in[2];
  const float* convW = (const float*)d_in[3];
  const float* convB = (const float*)d_in[4];
  const float* Wout  = (const float*)d_in[5];
  const float* bout  = (const float*)d_in[6];
  float* out = (float*)d_out;

  hipLaunchKernelGGL(gcn_fused, dim3(NBLK), dim3(512), 0, stream,
                     emb, W_emb, b_emb, convW, convB, Wout, bout, out);
}